// Round 1
// baseline (418.739 us; speedup 1.0000x reference)
//
#include <hip/hip_runtime.h>
#include <stdint.h>

// Problem shape (fixed by reference): x[4,2048,4096] f32, CB[4096,4096] i8, SCB[4096] f32
static constexpr int Mtot = 8192;   // B*S
static constexpr int Ntot = 4096;   // OUT
static constexpr int Ktot = 4096;   // IN

using i32x4 = __attribute__((ext_vector_type(4))) int;

#define GLD16(gptr, lptr)                                                                   \
  __builtin_amdgcn_global_load_lds((const __attribute__((address_space(1))) void*)(gptr),   \
                                   (__attribute__((address_space(3))) void*)(lptr), 16, 0, 0)

// ---------------------------------------------------------------------------
// Kernel 1: repack CB from harness int32 to int8 (16 MB in ws).
// ---------------------------------------------------------------------------
__global__ __launch_bounds__(256) void pack_cb_kernel(const int* __restrict__ src,
                                                      int8_t* __restrict__ dst) {
  const int idx = blockIdx.x * 256 + threadIdx.x;  // one int4 -> one packed int
  const int4 v = reinterpret_cast<const int4*>(src)[idx];
  const unsigned packed = (unsigned)(v.x & 0xff) | ((unsigned)(v.y & 0xff) << 8) |
                          ((unsigned)(v.z & 0xff) << 16) | ((unsigned)(v.w & 0xff) << 24);
  reinterpret_cast<unsigned*>(dst)[idx] = packed;
}

// ---------------------------------------------------------------------------
// Kernel 2: row-wise dynamic int8 quant of x. One block per row (K=4096).
// sx[row] = absmax/127 ; xq = rint(x * 127/absmax)  (rint == round-half-even,
// matching jnp.round).
// ---------------------------------------------------------------------------
__global__ __launch_bounds__(256) void quant_x_kernel(const float* __restrict__ x,
                                                      int8_t* __restrict__ xq,
                                                      float* __restrict__ sx) {
  const int row = blockIdx.x;
  const float4* xr = reinterpret_cast<const float4*>(x + (size_t)row * Ktot);
  float4 v[4];
  float am = 0.f;
#pragma unroll
  for (int i = 0; i < 4; ++i) {
    v[i] = xr[threadIdx.x + i * 256];
    am = fmaxf(am, fmaxf(fmaxf(fabsf(v[i].x), fabsf(v[i].y)),
                         fmaxf(fabsf(v[i].z), fabsf(v[i].w))));
  }
#pragma unroll
  for (int off = 32; off > 0; off >>= 1) am = fmaxf(am, __shfl_xor(am, off));
  __shared__ float wmax[4];
  if ((threadIdx.x & 63) == 0) wmax[threadIdx.x >> 6] = am;
  __syncthreads();
  am = fmaxf(fmaxf(wmax[0], wmax[1]), fmaxf(wmax[2], wmax[3]));
  const float inv = 127.0f / am;
  if (threadIdx.x == 0) sx[row] = am * (1.0f / 127.0f);
  unsigned* dq = reinterpret_cast<unsigned*>(xq + (size_t)row * Ktot);
#pragma unroll
  for (int i = 0; i < 4; ++i) {
    const int q0 = (int)rintf(v[i].x * inv);
    const int q1 = (int)rintf(v[i].y * inv);
    const int q2 = (int)rintf(v[i].z * inv);
    const int q3 = (int)rintf(v[i].w * inv);
    dq[threadIdx.x + i * 256] = (unsigned)(q0 & 0xff) | ((unsigned)(q1 & 0xff) << 8) |
                                ((unsigned)(q2 & 0xff) << 16) | ((unsigned)(q3 & 0xff) << 24);
  }
}

// ---------------------------------------------------------------------------
// Kernel 3: int8 GEMM, m97/m145-ladder structure.
// A = xq [M,K] K-contig, B = CB [N,K] K-contig (gemm_bt layout).
// 128x128 tile, BK=64, 256 threads = 4 waves, each wave 64x64 via 4x4 grid of
// mfma_i32_16x16x64_i8. Fused dequant epilogue: y = acc * sx[m] * SCB[n]/127.
// ---------------------------------------------------------------------------
__global__ __launch_bounds__(256) void gemm_i8_kernel(const int8_t* __restrict__ A,
                                                      const int8_t* __restrict__ B,
                                                      const float* __restrict__ sx,
                                                      const float* __restrict__ scb,
                                                      float* __restrict__ C) {
  constexpr int BK = 64;
  __shared__ int8_t As[128 * BK];  // 8 KB, [row][k] row-major
  __shared__ int8_t Bs[128 * BK];  // 8 KB

  const int tid = threadIdx.x;
  const int lane = tid & 63;
  const int wid = tid >> 6;
  const int m0 = blockIdx.y * 128;
  const int n0 = blockIdx.x * 128;
  const int wm = (wid >> 1) * 64;  // wave's 64x64 sub-tile
  const int wn = (wid & 1) * 64;

  // staging map: linear idx = issue*256 + tid; row = idx/4, kcol = (idx%4)*16.
  // LDS dest = base + tid*16 — contiguous in exactly lane order (G-load-lds
  // requires wave-uniform base + lane*16; no padding possible).
  const int srow = tid >> 2;
  const int scol = (tid & 3) * 16;
  const int8_t* Ag0 = A + (size_t)(m0 + srow) * Ktot + scol;
  const int8_t* Ag1 = A + (size_t)(m0 + 64 + srow) * Ktot + scol;
  const int8_t* Bg0 = B + (size_t)(n0 + srow) * Ktot + scol;
  const int8_t* Bg1 = B + (size_t)(n0 + 64 + srow) * Ktot + scol;
  int8_t* lA0 = &As[tid * 16];
  int8_t* lA1 = &As[4096 + tid * 16];
  int8_t* lB0 = &Bs[tid * 16];
  int8_t* lB1 = &Bs[4096 + tid * 16];

  i32x4 acc[4][4];
#pragma unroll
  for (int i = 0; i < 4; ++i)
#pragma unroll
    for (int j = 0; j < 4; ++j) acc[i][j] = (i32x4)0;

  // A-frag: lane holds row (lane&15), k-bytes [(lane>>4)*16, +16) — same byte
  // pattern as the verified bf16 16x16x32 layout (16 B per lane per quad).
  const int mrow = lane & 15;
  const int kq = (lane >> 4) * 16;

  for (int kt = 0; kt < Ktot; kt += BK) {
    GLD16(Ag0 + kt, lA0);
    GLD16(Ag1 + kt, lA1);
    GLD16(Bg0 + kt, lB0);
    GLD16(Bg1 + kt, lB1);
    __syncthreads();  // compiler emits vmcnt(0) drain before s_barrier

    i32x4 af[4], bf[4];
#pragma unroll
    for (int i = 0; i < 4; ++i)
      af[i] = *reinterpret_cast<const i32x4*>(&As[(wm + i * 16 + mrow) * BK + kq]);
#pragma unroll
    for (int j = 0; j < 4; ++j)
      bf[j] = *reinterpret_cast<const i32x4*>(&Bs[(wn + j * 16 + mrow) * BK + kq]);
#pragma unroll
    for (int i = 0; i < 4; ++i)
#pragma unroll
      for (int j = 0; j < 4; ++j)
        acc[i][j] = __builtin_amdgcn_mfma_i32_16x16x64_i8(af[i], bf[j], acc[i][j], 0, 0, 0);
    __syncthreads();
  }

  // Epilogue: C/D layout col=lane&15, row=(lane>>4)*4+reg (HW-verified,
  // dtype-independent). y = acc * sx[m] * (SCB[n]/127).
  const int col = lane & 15;
  const int rbase = (lane >> 4) * 4;
#pragma unroll
  for (int i = 0; i < 4; ++i) {
    const int gmb = m0 + wm + i * 16 + rbase;
    float sm[4];
#pragma unroll
    for (int r = 0; r < 4; ++r) sm[r] = sx[gmb + r];
#pragma unroll
    for (int j = 0; j < 4; ++j) {
      const int gn = n0 + wn + j * 16 + col;
      const float snv = scb[gn] * (1.0f / 127.0f);
#pragma unroll
      for (int r = 0; r < 4; ++r)
        C[(size_t)(gmb + r) * Ntot + gn] = (float)acc[i][j][r] * sm[r] * snv;
    }
  }
}

// ---------------------------------------------------------------------------
extern "C" void kernel_launch(void* const* d_in, const int* in_sizes, int n_in,
                              void* d_out, int out_size, void* d_ws, size_t ws_size,
                              hipStream_t stream) {
  const float* x = (const float*)d_in[0];
  const int* CB32 = (const int*)d_in[1];   // harness: integer inputs -> const int*
  const float* SCB = (const float*)d_in[2];
  float* out = (float*)d_out;

  // ws layout: xq (32 MB) | cb8 (16 MB) | sx (32 KB)  => needs ~48.03 MB
  int8_t* xq = (int8_t*)d_ws;
  int8_t* cb8 = (int8_t*)d_ws + (size_t)Mtot * Ktot;
  float* sx = (float*)((int8_t*)d_ws + (size_t)Mtot * Ktot + (size_t)Ntot * Ktot);

  pack_cb_kernel<<<(Ntot * Ktot / 4) / 256, 256, 0, stream>>>(CB32, cb8);
  quant_x_kernel<<<Mtot, 256, 0, stream>>>(x, xq, sx);
  dim3 grid(Ntot / 128, Mtot / 128);  // (32, 64)
  gemm_i8_kernel<<<grid, 256, 0, stream>>>(xq, cb8, sx, SCB, out);
}